// Round 11
// baseline (202.124 us; speedup 1.0000x reference)
//
#include <hip/hip_runtime.h>
#include <math.h>

// Problem constants (from reference): B=2, S=2048, D=1024, H=16, DH=64
#define BATCH 2
#define SEQ 2048
#define DMODEL 1024
#define NHEAD 16
#define DHEAD 64
#define QKV_COLS (3 * DMODEL)          // 3072
#define EPS 1e-8f
#define LOG2E 1.44269504f

typedef short bf16x8 __attribute__((ext_vector_type(8)));   // 8 bf16 (4 VGPRs)
typedef float f32x4 __attribute__((ext_vector_type(4)));    // 4 fp32 acc

// round-to-nearest-even float -> bf16 (as raw ushort)
static __device__ __forceinline__ unsigned short f2bf(float x) {
  unsigned u = __float_as_uint(x);
  u += 0x7fffu + ((u >> 16) & 1u);
  return (unsigned short)(u >> 16);
}

// pack two f32 -> one u32 of 2xbf16 in ONE VALU op (T12 recipe)
static __device__ __forceinline__ unsigned cvtpk(float lo, float hi) {
  unsigned r;
  asm("v_cvt_pk_bf16_f32 %0, %1, %2" : "=v"(r) : "v"(lo), "v"(hi));
  return r;
}

// async global->LDS, 16 B per lane (global_load_lds_dwordx4).
// LDS dest: wave-uniform base + lane*16 (m104/m108).
static __device__ __forceinline__ void async_ld16(const unsigned short* g,
                                                  unsigned short* l) {
  __builtin_amdgcn_global_load_lds(
      (const __attribute__((address_space(1))) void*)g,
      (__attribute__((address_space(3))) void*)(unsigned int)(unsigned long long)l,
      16, 0, 0);
}

// ---------------------------------------------------------------------------
// Prep (fused): x f32->bf16 copy + both weight transposes, one launch.
// blocks 0..4095: convert; 4096..8191: transpose (block-uniform branch).
// ---------------------------------------------------------------------------
__global__ __launch_bounds__(256) void prep_kernel(
    const float* __restrict__ x, unsigned short* __restrict__ xb,
    const float* __restrict__ W0, unsigned short* __restrict__ Wt0,
    const float* __restrict__ W1, unsigned short* __restrict__ Wt1) {
  __shared__ float tile[32][33];
  const int bid = blockIdx.x;
  if (bid < 4096) {
    const size_t i = ((size_t)bid * 256 + threadIdx.x) * 4;
    const float4 a = *(const float4*)(x + i);
    ushort4 r;
    r.x = f2bf(a.x); r.y = f2bf(a.y); r.z = f2bf(a.z); r.w = f2bf(a.w);
    *(ushort4*)(xb + i) = r;
    return;
  }
  const int bxx = bid - 4096;
  const int bxi = bxx & 127;          // 0..127 (n-block)
  const int k0 = (bxx >> 7) * 32;     // 0..31 -> k offset
  const float* W;
  unsigned short* Wt;
  int N, n0;
  if (bxi < 96) { W = W0; Wt = Wt0; N = QKV_COLS; n0 = bxi * 32; }
  else          { W = W1; Wt = Wt1; N = DMODEL;   n0 = (bxi - 96) * 32; }
  const int K = DMODEL;
  const int tx = threadIdx.x & 31, ty = threadIdx.x >> 5;
#pragma unroll
  for (int i = 0; i < 4; ++i)
    tile[ty + i * 8][tx] = W[(size_t)(k0 + ty + i * 8) * N + n0 + tx];
  __syncthreads();
#pragma unroll
  for (int i = 0; i < 4; ++i)
    Wt[(size_t)(n0 + ty + i * 8) * K + k0 + tx] = f2bf(tile[tx][ty + i * 8]);
}

// ---------------------------------------------------------------------------
// GEMM2 — R17 form (proven best): 64x128 tiles, grid (8,64) = 512 blocks =
// 2/CU, XCD + chunk-XOR LDS swizzle. C = A @ Bt^T, f32 out.
// ---------------------------------------------------------------------------
__global__ __launch_bounds__(256) void sgemm_bf16_kernel(
    const unsigned short* __restrict__ A, const unsigned short* __restrict__ Bt,
    float* __restrict__ C, int M, int N, int K) {
  __shared__ unsigned short As[2][64 * 32];    // [buf][m][k]   4 KiB each
  __shared__ unsigned short Bs[2][128 * 32];   // [buf][n][k]   8 KiB each

  const int t = threadIdx.x;
  const int w = t >> 6;
  const int lane = t & 63;
  const int quad = lane >> 4;
  const int lr = lane & 15;
  const int rk = (lr >> 1) & 3;      // read-side XOR key = (row>>1)&3

  // T1 swizzle: dispatch-linear id -> XCD-chunked logical id (512 %% 8 == 0)
  const int orig = blockIdx.y * gridDim.x + blockIdx.x;   // gridDim.x == 8
  const int wg = (orig & 7) * 64 + (orig >> 3);
  const int bx = wg & 7, by = wg >> 3;                    // by: 0..63
  const int m0 = by * 64;
  const int n0 = bx * 128;

  const int srow = lane >> 2;                              // 0..15
  const int scol = ((lane & 3) ^ ((lane >> 3) & 3)) * 8;   // pre-swizzled chunk

  // 12 async_ld16 per K-step: 4 A-quarters (16 rows) + 8 B-eighths.
  auto stage = [&](int k0, int bb) {
#pragma unroll
    for (int ii = 0; ii < 3; ++ii) {
      const int fi = w * 3 + ii;
      if (fi < 4) {
        async_ld16(A + (size_t)(m0 + fi * 16 + srow) * K + k0 + scol,
                   &As[bb][fi * 512]);
      } else {
        const int g = fi - 4;
        async_ld16(Bt + (size_t)(n0 + g * 16 + srow) * K + k0 + scol,
                   &Bs[bb][g * 512]);
      }
    }
  };

  f32x4 acc[4][2];
  const f32x4 zero4 = {0.f, 0.f, 0.f, 0.f};
#pragma unroll
  for (int i = 0; i < 4; ++i)
#pragma unroll
    for (int j = 0; j < 2; ++j) acc[i][j] = zero4;

  stage(0, 0);
  int bb = 0;
  for (int k0 = 0; k0 < K; k0 += 32, bb ^= 1) {
    __syncthreads();
    if (k0 + 32 < K) stage(k0 + 32, bb ^ 1);

    bf16x8 af[4], bfr[2];
#pragma unroll
    for (int i = 0; i < 4; ++i)
      af[i] = *(const bf16x8*)&As[bb][(i * 16 + lr) * 32 + ((quad ^ rk) * 8)];
#pragma unroll
    for (int j = 0; j < 2; ++j)
      bfr[j] = *(const bf16x8*)&Bs[bb][(w * 32 + j * 16 + lr) * 32 + ((quad ^ rk) * 8)];
#pragma unroll
    for (int i = 0; i < 4; ++i)
#pragma unroll
      for (int j = 0; j < 2; ++j)
        acc[i][j] = __builtin_amdgcn_mfma_f32_16x16x32_bf16(af[i], bfr[j], acc[i][j], 0, 0, 0);
  }

#pragma unroll
  for (int i = 0; i < 4; ++i)
#pragma unroll
    for (int r = 0; r < 4; ++r) {
      float* c = C + (size_t)(m0 + i * 16 + quad * 4 + r) * N + n0 + w * 32 + lr;
#pragma unroll
      for (int j = 0; j < 2; ++j) c[j * 16] = acc[i][j][r];
    }
}

// ---------------------------------------------------------------------------
// GEMM1 + fused qk-norm — R17 form (proven best, 42 us): 128x128 2-phase +
// T1 XCD swizzle + chunk-XOR LDS swizzle.
// ---------------------------------------------------------------------------
__global__ __launch_bounds__(256) void qkv_gemm_norm_kernel(
    const unsigned short* __restrict__ A, const unsigned short* __restrict__ Bt,
    const float* __restrict__ tau,
    unsigned short* __restrict__ Qh, unsigned short* __restrict__ Kh,
    unsigned short* __restrict__ Vh) {
  __shared__ unsigned short As[2][128 * 32];
  __shared__ unsigned short Bs[2][128 * 32];

  const int K = DMODEL;
  const int t = threadIdx.x;
  const int w = t >> 6;
  const int lane = t & 63;
  const int quad = lane >> 4;
  const int lr = lane & 15;
  const int wr = w >> 1, wc = w & 1;
  const int rk = (lr >> 1) & 3;      // read-side XOR key

  // T1 swizzle: 768 blocks (24 x 32) -> XCD k gets 96 contiguous ids.
  const int orig = blockIdx.y * gridDim.x + blockIdx.x;   // gridDim.x == 24
  const int wg = (orig & 7) * 96 + (orig >> 3);
  const int bx = wg % 24, by = wg / 24;
  const int m0 = by * 128;
  const int n0 = bx * 128;

  const int srow = w * 32 + (lane >> 2);
  const int scol = ((lane & 3) ^ ((lane >> 3) & 3)) * 8;   // pre-swizzled chunk
  const unsigned short* ga = A + (size_t)(m0 + srow) * K + scol;
  const unsigned short* gb = Bt + (size_t)(n0 + srow) * K + scol;

  auto stage = [&](int k0, int bb) {
#pragma unroll
    for (int i = 0; i < 2; ++i) {
      async_ld16(ga + (size_t)(i * 16) * K + k0, &As[bb][(w * 32 + i * 16) * 32]);
      async_ld16(gb + (size_t)(i * 16) * K + k0, &Bs[bb][(w * 32 + i * 16) * 32]);
    }
  };

  f32x4 acc[4][4];
  const f32x4 zero4 = {0.f, 0.f, 0.f, 0.f};
#pragma unroll
  for (int i = 0; i < 4; ++i)
#pragma unroll
    for (int j = 0; j < 4; ++j) acc[i][j] = zero4;

  stage(0, 0);
  int bb = 0;
  for (int k0 = 0; k0 < K; k0 += 32, bb ^= 1) {
    __syncthreads();
    if (k0 + 32 < K) stage(k0 + 32, bb ^ 1);

    bf16x8 af[4], bfr[4];
#pragma unroll
    for (int i = 0; i < 4; ++i)
      af[i] = *(const bf16x8*)&As[bb][(wr * 64 + i * 16 + lr) * 32 + ((quad ^ rk) * 8)];
#pragma unroll
    for (int j = 0; j < 4; ++j)
      bfr[j] = *(const bf16x8*)&Bs[bb][(wc * 64 + j * 16 + lr) * 32 + ((quad ^ rk) * 8)];
#pragma unroll
    for (int i = 0; i < 4; ++i)
#pragma unroll
      for (int j = 0; j < 4; ++j)
        acc[i][j] = __builtin_amdgcn_mfma_f32_16x16x32_bf16(af[i], bfr[j], acc[i][j], 0, 0, 0);
  }

  // Epilogue: wave-uniform (which, head) from column block.
  const int col0 = n0 + wc * 64;
  const int which = col0 >> 10;             // 0=q, 1=k, 2=v
  const int h = (col0 & 1023) >> 6;
  const float tsc = tau[h] * 0.125f * LOG2E;
  unsigned short* dst = (which == 0) ? Qh : (which == 1) ? Kh : Vh;

#pragma unroll
  for (int i = 0; i < 4; ++i)
#pragma unroll
    for (int r = 0; r < 4; ++r) {
      const int s = m0 + wr * 64 + i * 16 + quad * 4 + r;   // global row 0..4095
      unsigned short* ar =
          dst + (((size_t)((s >> 11) * NHEAD + h)) * SEQ + (s & 2047)) * DHEAD;
      float scale;
      if (which == 2) {
        scale = 1.0f;
      } else {
        float ss = 0.f;
#pragma unroll
        for (int j = 0; j < 4; ++j) ss += acc[i][j][r] * acc[i][j][r];
        ss += __shfl_xor(ss, 1, 16);
        ss += __shfl_xor(ss, 2, 16);
        ss += __shfl_xor(ss, 4, 16);
        ss += __shfl_xor(ss, 8, 16);
        scale = 1.0f / (sqrtf(ss) + EPS);
        if (which == 0) scale *= tsc;       // tau/sqrt(DH) * log2e into Q
      }
#pragma unroll
      for (int j = 0; j < 4; ++j) ar[j * 16 + lr] = f2bf(acc[i][j][r] * scale);
    }
}

// ---------------------------------------------------------------------------
// V transpose: Vh [BH][S][DH] -> Vt [BH][DH][S]. 64x64 LDS tiles.
// ---------------------------------------------------------------------------
__global__ __launch_bounds__(256) void vtrans_kernel(
    const unsigned short* __restrict__ Vh, unsigned short* __restrict__ Vt) {
  __shared__ unsigned short tile[64][72];
  const int bh = blockIdx.x;
  const int s0 = blockIdx.y * 64;
  const int t = threadIdx.x;
  const int sr = t >> 2;          // 0..63
  const int dc = (t & 3) * 16;    // 0,16,32,48
  const unsigned short* src = Vh + ((size_t)bh * SEQ + s0 + sr) * DHEAD + dc;
  *(bf16x8*)&tile[sr][dc]     = *(const bf16x8*)(src);
  *(bf16x8*)&tile[sr][dc + 8] = *(const bf16x8*)(src + 8);
  __syncthreads();
  const int dr = t >> 2;          // 0..63 (d row)
  const int sc = (t & 3) * 16;    // s chunk
  unsigned short buf[16];
#pragma unroll
  for (int i = 0; i < 16; ++i) buf[i] = tile[sc + i][dr];
  unsigned short* dst = Vt + ((size_t)bh * DHEAD + dr) * SEQ + s0 + sc;
  *(bf16x8*)dst       = *(const bf16x8*)buf;
  *(bf16x8*)(dst + 8) = *(const bf16x8*)(buf + 8);
}

// ---------------------------------------------------------------------------
// Causal flash attention — R21 (resubmitted; R21's bench was an infra
// failure, no data). q-AMORTIZATION: each wave owns 32 q-rows (two 16-row
// groups A/B) per 64-key step; the q-independent K-frags (kf[8]) and
// V-frags (vb[4]/c2) are read from LDS ONCE and reused for both groups.
// Per unit of work this halves: LDS reads, barriers+drains, and global
// staging (276 -> 139 MB). MFMA/work and VALU/work unchanged (+3% waste
// from group-A skip on the final step).
// Block = 128 q-rows, grid 512 = 2 blocks/CU; pairing qb = s<8 ? 15-s : s-8
// makes the resident pair (idx, idx+256) sum to exactly 34 steps AND share
// the same bh (same K/V stream in L2). Longest blocks dispatch first.
// Group A skips the final step entirely (block-uniform branch; kA and k0
// are block-uniform, so no divergent-barrier hazard).
// ---------------------------------------------------------------------------
__global__ __launch_bounds__(256, 2) void attn_kernel(
    const unsigned short* __restrict__ Qh, const unsigned short* __restrict__ Kh,
    const unsigned short* __restrict__ Vt, unsigned short* __restrict__ attnb) {
  __shared__ unsigned short Ks[2][64 * 64];   // [buf][key][d']  swizzled chunks
  __shared__ unsigned short Vs[2][64 * 64];   // [buf][d][key']  swizzled chunks

  const int idx = blockIdx.x;
  const int bh = idx & 31;
  const int sl = idx >> 5;                  // 0..15
  const int qb = (sl < 8) ? 15 - sl : sl - 8;   // q-128-block index
  const int b = bh >> 4;
  const int h = bh & 15;
  const int t = threadIdx.x;
  const int w = t >> 6;
  const int lane = t & 63;
  const int quad = lane >> 4;
  const int lr = lane & 15;
  const int sw = lr & 7;                   // read-side XOR swizzle key (row&7)

  const unsigned short* Qp = Qh + (size_t)bh * SEQ * DHEAD;
  const unsigned short* Kp = Kh + (size_t)bh * SEQ * DHEAD;
  const unsigned short* Vp = Vt + (size_t)bh * DHEAD * SEQ;

  const int rrow = lane >> 3;                        // 0..7
  const int swc = ((lane & 7) ^ rrow) * 8;           // swizzled chunk, in shorts
  const int f0 = w * 4;

  auto stage = [&](int k0, int bb) {
#pragma unroll
    for (int ii = 0; ii < 4; ++ii) {
      const int fi = f0 + ii;
      if (fi < 8) {   // K tile rows = keys
        async_ld16(Kp + (size_t)(k0 + fi * 8 + rrow) * DHEAD + swc,
                   &Ks[bb][fi * 512]);
      } else {        // V^T tile rows = d
        const int g = fi - 8;
        async_ld16(Vp + (size_t)(g * 8 + rrow) * SEQ + k0 + swc,
                   &Vs[bb][g * 512]);
      }
    }
  };

  const f32x4 zero4 = {0.f, 0.f, 0.f, 0.f};
  f32x4 oA[4], oB[4];
  oA[0] = oA[1] = oA[2] = oA[3] = zero4;
  oB[0] = oB[1] = oB[2] = oB[3] = zero4;
  f32x4 olA = zero4, olB = zero4;          // row-sum accumulators

  bf16x8 ones;
#pragma unroll
  for (int i = 0; i < 8; ++i) ones[i] = (short)0x3F80;   // bf16 1.0

  const int qbase = qb * 128;
  const int q0A = qbase + w * 16;
  const int q0B = qbase + 64 + w * 16;
  const unsigned short* qrA = Qp + (size_t)(q0A + lr) * DHEAD;
  const unsigned short* qrB = Qp + (size_t)(q0B + lr) * DHEAD;
  const bf16x8 aqA0 = *(const bf16x8*)(qrA + quad * 8);
  const bf16x8 aqA1 = *(const bf16x8*)(qrA + 32 + quad * 8);
  const bf16x8 aqB0 = *(const bf16x8*)(qrB + quad * 8);
  const bf16x8 aqB1 = *(const bf16x8*)(qrB + 32 + quad * 8);
  const int qrowA = q0A + lr;
  const int qrowB = q0B + lr;

  const int kA = qbase;            // group A's diagonal step (then A done)
  const int kend = qbase + 64;     // group B's diagonal step (= last step)

  // softmax + pack (fixed-max exp2, cvt_pk)
  auto smpack = [&](const f32x4* c, int k0, bool msk, int qrow,
                    unsigned* plo, unsigned* phi) {
    if (msk) {
#pragma unroll
      for (int kt = 0; kt < 4; ++kt) {
        float p[4];
#pragma unroll
        for (int r = 0; r < 4; ++r) {
          const int key = k0 + kt * 16 + quad * 4 + r;
          p[r] = (key <= qrow) ? exp2f(c[kt][r]) : 0.f;
        }
        plo[kt] = cvtpk(p[0], p[1]);
        phi[kt] = cvtpk(p[2], p[3]);
      }
    } else {
#pragma unroll
      for (int kt = 0; kt < 4; ++kt) {
        plo[kt] = cvtpk(exp2f(c[kt][0]), exp2f(c[kt][1]));
        phi[kt] = cvtpk(exp2f(c[kt][2]), exp2f(c[kt][3]));
      }
    }
  };

  // permlane butterfly + PV accumulate for one group / c2 half
  auto pvacc = [&](const unsigned* plo, const unsigned* phi, int c2,
                   const bf16x8* vb, f32x4* o, f32x4& ol) {
    unsigned aLo = plo[2 * c2],     aHi = phi[2 * c2];
    unsigned bLo = plo[2 * c2 + 1], bHi = phi[2 * c2 + 1];
    asm("v_permlane32_swap_b32 %0, %1" : "+v"(aLo), "+v"(bLo));
    asm("v_permlane32_swap_b32 %0, %1" : "+v"(aHi), "+v"(bHi));
    asm("v_permlane16_swap_b32 %0, %1" : "+v"(aLo), "+v"(bLo));
    asm("v_permlane16_swap_b32 %0, %1" : "+v"(aHi), "+v"(bHi));
    union { unsigned u[4]; bf16x8 v; } pk;
    pk.u[0] = aLo; pk.u[1] = aHi; pk.u[2] = bLo; pk.u[3] = bHi;
    const bf16x8 pa = pk.v;
    __builtin_amdgcn_s_setprio(1);
#pragma unroll
    for (int nt = 0; nt < 4; ++nt)
      o[nt] = __builtin_amdgcn_mfma_f32_16x16x32_bf16(pa, vb[nt], o[nt], 0, 0, 0);
    ol = __builtin_amdgcn_mfma_f32_16x16x32_bf16(pa, ones, ol, 0, 0, 0);
    __builtin_amdgcn_s_setprio(0);
  };

  stage(0, 0);
  int bb = 0;

  for (int k0 = 0; k0 <= kend; k0 += 64, bb ^= 1) {
    __syncthreads();                       // buf bb staged; prev reads done
    if (k0 < kend) stage(k0 + 64, bb ^ 1);

    // K fragments — read ONCE, shared by both q-groups
    bf16x8 kf0[4], kf1[4];
#pragma unroll
    for (int kt = 0; kt < 4; ++kt) {
      kf0[kt] = *(const bf16x8*)&Ks[bb][(kt * 16 + lr) * 64 + ((quad ^ sw) * 8)];
      kf1[kt] = *(const bf16x8*)&Ks[bb][(kt * 16 + lr) * 64 + (((4 | quad) ^ sw) * 8)];
    }

    const bool actA = (k0 <= kA);          // block-uniform
    unsigned ploA[4], phiA[4], ploB[4], phiB[4];

    if (actA) {
      f32x4 c[4];
      __builtin_amdgcn_s_setprio(1);
#pragma unroll
      for (int kt = 0; kt < 4; ++kt) {
        f32x4 tt = __builtin_amdgcn_mfma_f32_16x16x32_bf16(kf0[kt], aqA0, zero4, 0, 0, 0);
        c[kt] = __builtin_amdgcn_mfma_f32_16x16x32_bf16(kf1[kt], aqA1, tt, 0, 0, 0);
      }
      __builtin_amdgcn_s_setprio(0);
      smpack(c, k0, k0 == kA, qrowA, ploA, phiA);
    }
    {
      f32x4 c[4];
      __builtin_amdgcn_s_setprio(1);
#pragma unroll
      for (int kt = 0; kt < 4; ++kt) {
        f32x4 tt = __builtin_amdgcn_mfma_f32_16x16x32_bf16(kf0[kt], aqB0, zero4, 0, 0, 0);
        c[kt] = __builtin_amdgcn_mfma_f32_16x16x32_bf16(kf1[kt], aqB1, tt, 0, 0, 0);
      }
      __builtin_amdgcn_s_setprio(0);
      smpack(c, k0, k0 == kend, qrowB, ploB, phiB);
    }

    // PV: V fragments read ONCE per c2, shared by both groups
#pragma unroll
    for (int c2 = 0; c2 < 2; ++c2) {
      bf16x8 vb[4];
#pragma unroll
      for (int nt = 0; nt < 4; ++nt)
        vb[nt] = *(const bf16x8*)&Vs[bb][(nt * 16 + lr) * 64 +
                                         (((c2 * 4 + quad) ^ sw) * 8)];
      if (actA) pvacc(ploA, phiA, c2, vb, oA, olA);
      pvacc(ploB, phiB, c2, vb, oB, olB);
    }
  }

  // epilogue: ol[r] is this lane's row-sum in C layout; no shuffles.
  auto epi = [&](int q0g, const f32x4* o, const f32x4& ol) {
#pragma unroll
    for (int r = 0; r < 4; ++r) {
      const float invr = 1.0f / ol[r];
      unsigned short* ar =
          attnb + ((size_t)(b * SEQ + q0g + quad * 4 + r)) * DMODEL + h * DHEAD;
#pragma unroll
      for (int nt = 0; nt < 4; ++nt) ar[nt * 16 + lr] = f2bf(o[nt][r] * invr);
    }
  };
  epi(q0A, oA, olA);
  epi(q0B, oB, olB);
}

// ---------------------------------------------------------------------------
// Launch
// ---------------------------------------------------------------------------
extern "C" void kernel_launch(void* const* d_in, const int* in_sizes, int n_in,
                              void* d_out, int out_size, void* d_ws, size_t ws_size,
                              hipStream_t stream) {
  const float* x    = (const float*)d_in[0];
  // d_in[1]: fixed causal tril mask -> handled analytically, never read.
  const float* Wqkv = (const float*)d_in[2];
  const float* Wo   = (const float*)d_in[3];
  const float* tau  = (const float*)d_in[4];
  float* out = (float*)d_out;

  // workspace layout (~50 MB)
  unsigned short* attnb = (unsigned short*)d_ws;                      // bf16 [B,S,D]
  unsigned short* Qh = attnb + (size_t)BATCH * SEQ * DMODEL;          // bf16 [B,H,S,DH]
  unsigned short* Kh = Qh + (size_t)BATCH * NHEAD * SEQ * DHEAD;
  unsigned short* Vh = Kh + (size_t)BATCH * NHEAD * SEQ * DHEAD;
  unsigned short* Xb = Vh + (size_t)BATCH * NHEAD * SEQ * DHEAD;      // bf16 [B*S][D]
  unsigned short* Wqkv_t = Xb + (size_t)BATCH * SEQ * DMODEL;         // bf16 [3D][D]
  unsigned short* Wo_t = Wqkv_t + (size_t)DMODEL * QKV_COLS;          // bf16 [D][D]
  unsigned short* Vt = Wo_t + (size_t)DMODEL * DMODEL;                // bf16 [BH][DH][S]

  const int M = BATCH * SEQ;  // 4096

  // 0) prep: fused bf16 conversion + both weight transposes (one launch)
  prep_kernel<<<dim3(8192), 256, 0, stream>>>(x, Xb, Wqkv, Wqkv_t, Wo, Wo_t);

  // 1) GEMM1 + fused qk-norm (R17 proven form) -> Qh/Kh/Vh
  qkv_gemm_norm_kernel<<<dim3(QKV_COLS / 128, M / 128), 256, 0, stream>>>(
      Xb, Wqkv_t, tau, Qh, Kh, Vh);

  // 2) V -> V^T [BH][DH][S]
  vtrans_kernel<<<dim3(BATCH * NHEAD, SEQ / 64), 256, 0, stream>>>(Vh, Vt);

  // 3) causal MFMA flash attention -> attnb bf16 [B,S,D]
  //    R21: 128-q blocks, grid 512, paired 34-step residency, shared-frag
  //    q-amortization (halved LDS/barrier/staging per unit work)
  attn_kernel<<<dim3(512), 256, 0, stream>>>(Qh, Kh, Vt, attnb);

  // 4) out = attn @ Wo  (M=4096, N=1024, K=1024), f32 out
  //    64x128 tiles, 512 blocks = 2/CU, XCD + LDS swizzle (R17 form)
  sgemm_bf16_kernel<<<dim3(DMODEL / 128, M / 64), 256, 0, stream>>>(
      attnb, Wo_t, out, M, DMODEL, DMODEL);
}

// Round 12
// 192.827 us; speedup vs baseline: 1.0482x; 1.0482x over previous
//
#include <hip/hip_runtime.h>
#include <math.h>

// Problem constants (from reference): B=2, S=2048, D=1024, H=16, DH=64
#define BATCH 2
#define SEQ 2048
#define DMODEL 1024
#define NHEAD 16
#define DHEAD 64
#define QKV_COLS (3 * DMODEL)          // 3072
#define EPS 1e-8f
#define LOG2E 1.44269504f

typedef short bf16x8 __attribute__((ext_vector_type(8)));   // 8 bf16 (4 VGPRs)
typedef float f32x4 __attribute__((ext_vector_type(4)));    // 4 fp32 acc

// round-to-nearest-even float -> bf16 (as raw ushort)
static __device__ __forceinline__ unsigned short f2bf(float x) {
  unsigned u = __float_as_uint(x);
  u += 0x7fffu + ((u >> 16) & 1u);
  return (unsigned short)(u >> 16);
}

// pack two f32 -> one u32 of 2xbf16 in ONE VALU op (T12 recipe)
static __device__ __forceinline__ unsigned cvtpk(float lo, float hi) {
  unsigned r;
  asm("v_cvt_pk_bf16_f32 %0, %1, %2" : "=v"(r) : "v"(lo), "v"(hi));
  return r;
}

// async global->LDS, 16 B per lane (global_load_lds_dwordx4).
// LDS dest: wave-uniform base + lane*16 (m104/m108).
static __device__ __forceinline__ void async_ld16(const unsigned short* g,
                                                  unsigned short* l) {
  __builtin_amdgcn_global_load_lds(
      (const __attribute__((address_space(1))) void*)g,
      (__attribute__((address_space(3))) void*)(unsigned int)(unsigned long long)l,
      16, 0, 0);
}

// ---------------------------------------------------------------------------
// Prep (fused): x f32->bf16 copy + both weight transposes, one launch.
// blocks 0..4095: convert; 4096..8191: transpose (block-uniform branch).
// ---------------------------------------------------------------------------
__global__ __launch_bounds__(256) void prep_kernel(
    const float* __restrict__ x, unsigned short* __restrict__ xb,
    const float* __restrict__ W0, unsigned short* __restrict__ Wt0,
    const float* __restrict__ W1, unsigned short* __restrict__ Wt1) {
  __shared__ float tile[32][33];
  const int bid = blockIdx.x;
  if (bid < 4096) {
    const size_t i = ((size_t)bid * 256 + threadIdx.x) * 4;
    const float4 a = *(const float4*)(x + i);
    ushort4 r;
    r.x = f2bf(a.x); r.y = f2bf(a.y); r.z = f2bf(a.z); r.w = f2bf(a.w);
    *(ushort4*)(xb + i) = r;
    return;
  }
  const int bxx = bid - 4096;
  const int bxi = bxx & 127;          // 0..127 (n-block)
  const int k0 = (bxx >> 7) * 32;     // 0..31 -> k offset
  const float* W;
  unsigned short* Wt;
  int N, n0;
  if (bxi < 96) { W = W0; Wt = Wt0; N = QKV_COLS; n0 = bxi * 32; }
  else          { W = W1; Wt = Wt1; N = DMODEL;   n0 = (bxi - 96) * 32; }
  const int K = DMODEL;
  const int tx = threadIdx.x & 31, ty = threadIdx.x >> 5;
#pragma unroll
  for (int i = 0; i < 4; ++i)
    tile[ty + i * 8][tx] = W[(size_t)(k0 + ty + i * 8) * N + n0 + tx];
  __syncthreads();
#pragma unroll
  for (int i = 0; i < 4; ++i)
    Wt[(size_t)(n0 + ty + i * 8) * K + k0 + tx] = f2bf(tile[tx][ty + i * 8]);
}

// ---------------------------------------------------------------------------
// GEMM2 — R17 form (proven best): 64x128 tiles, grid (8,64) = 512 blocks =
// 2/CU, XCD + chunk-XOR LDS swizzle. C = A @ Bt^T, f32 out.
// ---------------------------------------------------------------------------
__global__ __launch_bounds__(256) void sgemm_bf16_kernel(
    const unsigned short* __restrict__ A, const unsigned short* __restrict__ Bt,
    float* __restrict__ C, int M, int N, int K) {
  __shared__ unsigned short As[2][64 * 32];    // [buf][m][k]   4 KiB each
  __shared__ unsigned short Bs[2][128 * 32];   // [buf][n][k]   8 KiB each

  const int t = threadIdx.x;
  const int w = t >> 6;
  const int lane = t & 63;
  const int quad = lane >> 4;
  const int lr = lane & 15;
  const int rk = (lr >> 1) & 3;      // read-side XOR key = (row>>1)&3

  // T1 swizzle: dispatch-linear id -> XCD-chunked logical id (512 %% 8 == 0)
  const int orig = blockIdx.y * gridDim.x + blockIdx.x;   // gridDim.x == 8
  const int wg = (orig & 7) * 64 + (orig >> 3);
  const int bx = wg & 7, by = wg >> 3;                    // by: 0..63
  const int m0 = by * 64;
  const int n0 = bx * 128;

  const int srow = lane >> 2;                              // 0..15
  const int scol = ((lane & 3) ^ ((lane >> 3) & 3)) * 8;   // pre-swizzled chunk

  // 12 async_ld16 per K-step: 4 A-quarters (16 rows) + 8 B-eighths.
  auto stage = [&](int k0, int bb) {
#pragma unroll
    for (int ii = 0; ii < 3; ++ii) {
      const int fi = w * 3 + ii;
      if (fi < 4) {
        async_ld16(A + (size_t)(m0 + fi * 16 + srow) * K + k0 + scol,
                   &As[bb][fi * 512]);
      } else {
        const int g = fi - 4;
        async_ld16(Bt + (size_t)(n0 + g * 16 + srow) * K + k0 + scol,
                   &Bs[bb][g * 512]);
      }
    }
  };

  f32x4 acc[4][2];
  const f32x4 zero4 = {0.f, 0.f, 0.f, 0.f};
#pragma unroll
  for (int i = 0; i < 4; ++i)
#pragma unroll
    for (int j = 0; j < 2; ++j) acc[i][j] = zero4;

  stage(0, 0);
  int bb = 0;
  for (int k0 = 0; k0 < K; k0 += 32, bb ^= 1) {
    __syncthreads();
    if (k0 + 32 < K) stage(k0 + 32, bb ^ 1);

    bf16x8 af[4], bfr[2];
#pragma unroll
    for (int i = 0; i < 4; ++i)
      af[i] = *(const bf16x8*)&As[bb][(i * 16 + lr) * 32 + ((quad ^ rk) * 8)];
#pragma unroll
    for (int j = 0; j < 2; ++j)
      bfr[j] = *(const bf16x8*)&Bs[bb][(w * 32 + j * 16 + lr) * 32 + ((quad ^ rk) * 8)];
#pragma unroll
    for (int i = 0; i < 4; ++i)
#pragma unroll
      for (int j = 0; j < 2; ++j)
        acc[i][j] = __builtin_amdgcn_mfma_f32_16x16x32_bf16(af[i], bfr[j], acc[i][j], 0, 0, 0);
  }

#pragma unroll
  for (int i = 0; i < 4; ++i)
#pragma unroll
    for (int r = 0; r < 4; ++r) {
      float* c = C + (size_t)(m0 + i * 16 + quad * 4 + r) * N + n0 + w * 32 + lr;
#pragma unroll
      for (int j = 0; j < 2; ++j) c[j * 16] = acc[i][j][r];
    }
}

// ---------------------------------------------------------------------------
// GEMM1 + fused qk-norm — R17 form (proven best, 42 us): 128x128 2-phase +
// T1 XCD swizzle + chunk-XOR LDS swizzle. At its structure's documented
// 2-phase ceiling (614 TF ~= m233's 607); 7 escape levers measured null/neg.
// ---------------------------------------------------------------------------
__global__ __launch_bounds__(256) void qkv_gemm_norm_kernel(
    const unsigned short* __restrict__ A, const unsigned short* __restrict__ Bt,
    const float* __restrict__ tau,
    unsigned short* __restrict__ Qh, unsigned short* __restrict__ Kh,
    unsigned short* __restrict__ Vh) {
  __shared__ unsigned short As[2][128 * 32];
  __shared__ unsigned short Bs[2][128 * 32];

  const int K = DMODEL;
  const int t = threadIdx.x;
  const int w = t >> 6;
  const int lane = t & 63;
  const int quad = lane >> 4;
  const int lr = lane & 15;
  const int wr = w >> 1, wc = w & 1;
  const int rk = (lr >> 1) & 3;      // read-side XOR key

  // T1 swizzle: 768 blocks (24 x 32) -> XCD k gets 96 contiguous ids.
  const int orig = blockIdx.y * gridDim.x + blockIdx.x;   // gridDim.x == 24
  const int wg = (orig & 7) * 96 + (orig >> 3);
  const int bx = wg % 24, by = wg / 24;
  const int m0 = by * 128;
  const int n0 = bx * 128;

  const int srow = w * 32 + (lane >> 2);
  const int scol = ((lane & 3) ^ ((lane >> 3) & 3)) * 8;   // pre-swizzled chunk
  const unsigned short* ga = A + (size_t)(m0 + srow) * K + scol;
  const unsigned short* gb = Bt + (size_t)(n0 + srow) * K + scol;

  auto stage = [&](int k0, int bb) {
#pragma unroll
    for (int i = 0; i < 2; ++i) {
      async_ld16(ga + (size_t)(i * 16) * K + k0, &As[bb][(w * 32 + i * 16) * 32]);
      async_ld16(gb + (size_t)(i * 16) * K + k0, &Bs[bb][(w * 32 + i * 16) * 32]);
    }
  };

  f32x4 acc[4][4];
  const f32x4 zero4 = {0.f, 0.f, 0.f, 0.f};
#pragma unroll
  for (int i = 0; i < 4; ++i)
#pragma unroll
    for (int j = 0; j < 4; ++j) acc[i][j] = zero4;

  stage(0, 0);
  int bb = 0;
  for (int k0 = 0; k0 < K; k0 += 32, bb ^= 1) {
    __syncthreads();
    if (k0 + 32 < K) stage(k0 + 32, bb ^ 1);

    bf16x8 af[4], bfr[4];
#pragma unroll
    for (int i = 0; i < 4; ++i)
      af[i] = *(const bf16x8*)&As[bb][(wr * 64 + i * 16 + lr) * 32 + ((quad ^ rk) * 8)];
#pragma unroll
    for (int j = 0; j < 4; ++j)
      bfr[j] = *(const bf16x8*)&Bs[bb][(wc * 64 + j * 16 + lr) * 32 + ((quad ^ rk) * 8)];
#pragma unroll
    for (int i = 0; i < 4; ++i)
#pragma unroll
      for (int j = 0; j < 4; ++j)
        acc[i][j] = __builtin_amdgcn_mfma_f32_16x16x32_bf16(af[i], bfr[j], acc[i][j], 0, 0, 0);
  }

  // Epilogue: wave-uniform (which, head) from column block.
  const int col0 = n0 + wc * 64;
  const int which = col0 >> 10;             // 0=q, 1=k, 2=v
  const int h = (col0 & 1023) >> 6;
  const float tsc = tau[h] * 0.125f * LOG2E;
  unsigned short* dst = (which == 0) ? Qh : (which == 1) ? Kh : Vh;

#pragma unroll
  for (int i = 0; i < 4; ++i)
#pragma unroll
    for (int r = 0; r < 4; ++r) {
      const int s = m0 + wr * 64 + i * 16 + quad * 4 + r;   // global row 0..4095
      unsigned short* ar =
          dst + (((size_t)((s >> 11) * NHEAD + h)) * SEQ + (s & 2047)) * DHEAD;
      float scale;
      if (which == 2) {
        scale = 1.0f;
      } else {
        float ss = 0.f;
#pragma unroll
        for (int j = 0; j < 4; ++j) ss += acc[i][j][r] * acc[i][j][r];
        ss += __shfl_xor(ss, 1, 16);
        ss += __shfl_xor(ss, 2, 16);
        ss += __shfl_xor(ss, 4, 16);
        ss += __shfl_xor(ss, 8, 16);
        scale = 1.0f / (sqrtf(ss) + EPS);
        if (which == 0) scale *= tsc;       // tau/sqrt(DH) * log2e into Q
      }
#pragma unroll
      for (int j = 0; j < 4; ++j) ar[j * 16 + lr] = f2bf(acc[i][j][r] * scale);
    }
}

// ---------------------------------------------------------------------------
// V transpose: Vh [BH][S][DH] -> Vt [BH][DH][S]. 64x64 LDS tiles.
// ---------------------------------------------------------------------------
__global__ __launch_bounds__(256) void vtrans_kernel(
    const unsigned short* __restrict__ Vh, unsigned short* __restrict__ Vt) {
  __shared__ unsigned short tile[64][72];
  const int bh = blockIdx.x;
  const int s0 = blockIdx.y * 64;
  const int t = threadIdx.x;
  const int sr = t >> 2;          // 0..63
  const int dc = (t & 3) * 16;    // 0,16,32,48
  const unsigned short* src = Vh + ((size_t)bh * SEQ + s0 + sr) * DHEAD + dc;
  *(bf16x8*)&tile[sr][dc]     = *(const bf16x8*)(src);
  *(bf16x8*)&tile[sr][dc + 8] = *(const bf16x8*)(src + 8);
  __syncthreads();
  const int dr = t >> 2;          // 0..63 (d row)
  const int sc = (t & 3) * 16;    // s chunk
  unsigned short buf[16];
#pragma unroll
  for (int i = 0; i < 16; ++i) buf[i] = tile[sc + i][dr];
  unsigned short* dst = Vt + ((size_t)bh * DHEAD + dr) * SEQ + s0 + sc;
  *(bf16x8*)dst       = *(const bf16x8*)buf;
  *(bf16x8*)(dst + 8) = *(const bf16x8*)(buf + 8);
}

// ---------------------------------------------------------------------------
// Causal flash attention — R16 form restored (proven best; R21's
// q-amortization regressed: attn is TLP-bound, 2 blocks/CU halved
// occupancy 25->12.9% and dur 40->50 us).
// grid 1024, 4 blocks/CU, balanced qb mapping, XOR-swizzled K/V, P in
// registers via permlane swaps, cvt_pk packing, row-sum via MFMA-with-ones,
// setprio around MFMA clusters.
// ---------------------------------------------------------------------------
__global__ __launch_bounds__(256, 4) void attn_kernel(
    const unsigned short* __restrict__ Qh, const unsigned short* __restrict__ Kh,
    const unsigned short* __restrict__ Vt, unsigned short* __restrict__ attnb) {
  __shared__ unsigned short Ks[2][64 * 64];   // [buf][key][d']  swizzled chunks
  __shared__ unsigned short Vs[2][64 * 64];   // [buf][d][key']  swizzled chunks

  const int idx = blockIdx.x;
  const int bh = idx & 31;
  const int i2 = idx >> 5;                 // 0..31
  const int seg = i2 >> 3, G = i2 & 7;
  const int qb = (seg == 0) ? 31 - G : (seg == 1) ? G : (seg == 2) ? 23 - G : 8 + G;
  const int b = bh >> 4;
  const int h = bh & 15;
  const int t = threadIdx.x;
  const int w = t >> 6;
  const int lane = t & 63;
  const int quad = lane >> 4;
  const int lr = lane & 15;
  const int sw = lr & 7;                   // read-side XOR swizzle key (row&7)

  const unsigned short* Qp = Qh + (size_t)bh * SEQ * DHEAD;
  const unsigned short* Kp = Kh + (size_t)bh * SEQ * DHEAD;
  const unsigned short* Vp = Vt + (size_t)bh * DHEAD * SEQ;

  const int rrow = lane >> 3;                        // 0..7
  const int swc = ((lane & 7) ^ rrow) * 8;           // swizzled chunk, in shorts
  const int f0 = w * 4;

  auto stage = [&](int k0, int bb) {
#pragma unroll
    for (int ii = 0; ii < 4; ++ii) {
      const int fi = f0 + ii;
      if (fi < 8) {   // K tile rows = keys
        async_ld16(Kp + (size_t)(k0 + fi * 8 + rrow) * DHEAD + swc,
                   &Ks[bb][fi * 512]);
      } else {        // V^T tile rows = d
        const int g = fi - 8;
        async_ld16(Vp + (size_t)(g * 8 + rrow) * SEQ + k0 + swc,
                   &Vs[bb][g * 512]);
      }
    }
  };

  const f32x4 zero4 = {0.f, 0.f, 0.f, 0.f};
  f32x4 o[4];
  o[0] = o[1] = o[2] = o[3] = zero4;
  f32x4 ol = zero4;                 // row-sum accumulator (MFMA-with-ones)

  bf16x8 ones;
#pragma unroll
  for (int i = 0; i < 8; ++i) ones[i] = (short)0x3F80;   // bf16 1.0

  const int q0 = qb * 64 + w * 16;
  const unsigned short* qr = Qp + (size_t)(q0 + lr) * DHEAD;
  const bf16x8 aq0 = *(const bf16x8*)(qr + quad * 8);
  const bf16x8 aq1 = *(const bf16x8*)(qr + 32 + quad * 8);
  const int qrow = q0 + lr;        // this lane's q row (for diagonal mask)

  const int kend = qb * 64;        // last step's k0 (diagonal step)

  stage(0, 0);
  int bb = 0;

  for (int k0 = 0; k0 <= kend; k0 += 64, bb ^= 1) {
    __syncthreads();                       // buf bb staged; prev reads done
    if (k0 < kend) stage(k0 + 64, bb ^ 1);

    // --- QK^T (swapped: S^T = K * Q^T; lane holds 16 keys for q=lr) ---
    f32x4 c[4];
    __builtin_amdgcn_s_setprio(1);
#pragma unroll
    for (int kt = 0; kt < 4; ++kt) {
      const bf16x8 kf0 =
          *(const bf16x8*)&Ks[bb][(kt * 16 + lr) * 64 + ((quad ^ sw) * 8)];
      const bf16x8 kf1 =
          *(const bf16x8*)&Ks[bb][(kt * 16 + lr) * 64 + (((4 | quad) ^ sw) * 8)];
      f32x4 tt = __builtin_amdgcn_mfma_f32_16x16x32_bf16(kf0, aq0, zero4, 0, 0, 0);
      c[kt] = __builtin_amdgcn_mfma_f32_16x16x32_bf16(kf1, aq1, tt, 0, 0, 0);
    }
    __builtin_amdgcn_s_setprio(0);

    // --- fixed-max exp2 softmax, packed to bf16 via v_cvt_pk (1 VALU/pair)
    unsigned plo[4], phi[4];
    if (k0 == kend) {                      // diagonal step: causal mask
#pragma unroll
      for (int kt = 0; kt < 4; ++kt) {
        float p[4];
#pragma unroll
        for (int r = 0; r < 4; ++r) {
          const int key = k0 + kt * 16 + quad * 4 + r;
          p[r] = (key <= qrow) ? exp2f(c[kt][r]) : 0.f;
        }
        plo[kt] = cvtpk(p[0], p[1]);
        phi[kt] = cvtpk(p[2], p[3]);
      }
    } else {
#pragma unroll
      for (int kt = 0; kt < 4; ++kt) {
        plo[kt] = cvtpk(exp2f(c[kt][0]), exp2f(c[kt][1]));
        phi[kt] = cvtpk(exp2f(c[kt][2]), exp2f(c[kt][3]));
      }
    }

    // --- permlane butterfly: compute layout -> PV A-operand layout ---
#pragma unroll
    for (int c2 = 0; c2 < 2; ++c2) {
      unsigned aLo = plo[2 * c2],     aHi = phi[2 * c2];
      unsigned bLo = plo[2 * c2 + 1], bHi = phi[2 * c2 + 1];
      asm("v_permlane32_swap_b32 %0, %1" : "+v"(aLo), "+v"(bLo));
      asm("v_permlane32_swap_b32 %0, %1" : "+v"(aHi), "+v"(bHi));
      asm("v_permlane16_swap_b32 %0, %1" : "+v"(aLo), "+v"(bLo));
      asm("v_permlane16_swap_b32 %0, %1" : "+v"(aHi), "+v"(bHi));
      union { unsigned u[4]; bf16x8 v; } pk;
      pk.u[0] = aLo; pk.u[1] = aHi; pk.u[2] = bLo; pk.u[3] = bHi;
      const bf16x8 pa = pk.v;
      __builtin_amdgcn_s_setprio(1);
#pragma unroll
      for (int nt = 0; nt < 4; ++nt) {
        const bf16x8 vb = *(const bf16x8*)&Vs[bb][(nt * 16 + lr) * 64 +
                                                  (((c2 * 4 + quad) ^ sw) * 8)];
        o[nt] = __builtin_amdgcn_mfma_f32_16x16x32_bf16(pa, vb, o[nt], 0, 0, 0);
      }
      // row-sum: all 16 output cols identical = sum_k P[q][k]; accumulates
      // across steps. ol[r] = l for q = q0 + quad*4 + r (C layout).
      ol = __builtin_amdgcn_mfma_f32_16x16x32_bf16(pa, ones, ol, 0, 0, 0);
      __builtin_amdgcn_s_setprio(0);
    }
  }

  // epilogue: ol[r] is already this lane's row-sum in C layout; no shuffles.
#pragma unroll
  for (int r = 0; r < 4; ++r) {
    const float invr = 1.0f / ol[r];
    unsigned short* ar =
        attnb + ((size_t)(b * SEQ + q0 + quad * 4 + r)) * DMODEL + h * DHEAD;
#pragma unroll
    for (int nt = 0; nt < 4; ++nt) ar[nt * 16 + lr] = f2bf(o[nt][r] * invr);
  }
}

// ---------------------------------------------------------------------------
// Launch
// ---------------------------------------------------------------------------
extern "C" void kernel_launch(void* const* d_in, const int* in_sizes, int n_in,
                              void* d_out, int out_size, void* d_ws, size_t ws_size,
                              hipStream_t stream) {
  const float* x    = (const float*)d_in[0];
  // d_in[1]: fixed causal tril mask -> handled analytically, never read.
  const float* Wqkv = (const float*)d_in[2];
  const float* Wo   = (const float*)d_in[3];
  const float* tau  = (const float*)d_in[4];
  float* out = (float*)d_out;

  // workspace layout (~50 MB)
  unsigned short* attnb = (unsigned short*)d_ws;                      // bf16 [B,S,D]
  unsigned short* Qh = attnb + (size_t)BATCH * SEQ * DMODEL;          // bf16 [B,H,S,DH]
  unsigned short* Kh = Qh + (size_t)BATCH * NHEAD * SEQ * DHEAD;
  unsigned short* Vh = Kh + (size_t)BATCH * NHEAD * SEQ * DHEAD;
  unsigned short* Xb = Vh + (size_t)BATCH * NHEAD * SEQ * DHEAD;      // bf16 [B*S][D]
  unsigned short* Wqkv_t = Xb + (size_t)BATCH * SEQ * DMODEL;         // bf16 [3D][D]
  unsigned short* Wo_t = Wqkv_t + (size_t)DMODEL * QKV_COLS;          // bf16 [D][D]
  unsigned short* Vt = Wo_t + (size_t)DMODEL * DMODEL;                // bf16 [BH][DH][S]

  const int M = BATCH * SEQ;  // 4096

  // 0) prep: fused bf16 conversion + both weight transposes (one launch)
  prep_kernel<<<dim3(8192), 256, 0, stream>>>(x, Xb, Wqkv, Wqkv_t, Wo, Wo_t);

  // 1) GEMM1 + fused qk-norm (R17 proven form) -> Qh/Kh/Vh
  qkv_gemm_norm_kernel<<<dim3(QKV_COLS / 128, M / 128), 256, 0, stream>>>(
      Xb, Wqkv_t, tau, Qh, Kh, Vh);

  // 2) V -> V^T [BH][DH][S]
  vtrans_kernel<<<dim3(BATCH * NHEAD, SEQ / 64), 256, 0, stream>>>(Vh, Vt);

  // 3) causal MFMA flash attention -> attnb bf16 [B,S,D] (R16 proven form)
  attn_kernel<<<dim3(1024), 256, 0, stream>>>(Qh, Kh, Vt, attnb);

  // 4) out = attn @ Wo  (M=4096, N=1024, K=1024), f32 out
  //    64x128 tiles, 512 blocks = 2/CU, XCD + LDS swizzle (R17 form)
  sgemm_bf16_kernel<<<dim3(DMODEL / 128, M / 64), 256, 0, stream>>>(
      attnb, Wo_t, out, M, DMODEL, DMODEL);
}